// Round 8
// baseline (82.096 us; speedup 1.0000x reference)
//
#include <hip/hip_runtime.h>
#include <math.h>

#define N_NODES 50000
#define N_EDGES 800000
#define HIDDEN  256
#define OUT_DIM 10
#define LN_EPS  1e-5f

#define NP    8                    // node partitions
#define PART  (N_NODES / NP)       // 6250 nodes per partition
#define ES    32                   // edge slices
#define EPSE  (N_EDGES / ES)       // 25000 edges per slice
#define NPB   256                  // nodes per ln block
#define LNB   ((N_NODES + NPB - 1) / NPB)   // 196 blocks
#define NH2   (N_NODES / 2)        // 25000 node pairs

// --------------------------------------------------- privatized histogram ----
__global__ __launch_bounds__(1024) void hist_kernel(const int4* __restrict__ dst4,
                                                    unsigned* __restrict__ degp32) {
    __shared__ unsigned hist[PART];          // 25 KB
    const int tid = threadIdx.x;
    for (int i = tid; i < PART; i += 1024) hist[i] = 0u;
    __syncthreads();

    const int base = blockIdx.y * PART;
    const int b0 = blockIdx.x * (EPSE / 4);
    for (int i = tid; i < EPSE / 4; i += 1024) {
        const int4 d = dst4[b0 + i];
        unsigned r;
        r = (unsigned)(d.x - base); if (r < PART) atomicAdd(&hist[r], 1u);
        r = (unsigned)(d.y - base); if (r < PART) atomicAdd(&hist[r], 1u);
        r = (unsigned)(d.z - base); if (r < PART) atomicAdd(&hist[r], 1u);
        r = (unsigned)(d.w - base); if (r < PART) atomicAdd(&hist[r], 1u);
    }
    __syncthreads();

    unsigned* outp = degp32 + (size_t)blockIdx.x * NH2 + base / 2;
    for (int i = tid; i < PART / 2; i += 1024)
        outp[i] = (hist[2 * i] & 0xFFFFu) | (hist[2 * i + 1] << 16);
}

// deg partials -> dinv = rsqrt(deg+1), y = dinv * x   (2 nodes per thread)
__global__ __launch_bounds__(256) void dinv_y_kernel(const unsigned* __restrict__ degp32,
                                                     const float4* __restrict__ nf4,
                                                     float2* __restrict__ dinv2,
                                                     float4* __restrict__ y4) {
    const int t = blockIdx.x * 256 + threadIdx.x;   // pair index
    if (t >= NH2) return;
    unsigned s0 = 0, s1 = 0;
    #pragma unroll
    for (int s = 0; s < ES; ++s) {
        const unsigned d = degp32[(size_t)s * NH2 + t];
        s0 += d & 0xFFFFu;
        s1 += d >> 16;
    }
    const float di0 = rsqrtf((float)s0 + 1.0f);
    const float di1 = rsqrtf((float)s1 + 1.0f);
    dinv2[t] = make_float2(di0, di1);
    const float4 x = nf4[t];
    y4[t] = make_float4(di0 * x.x, di0 * x.y, di1 * x.z, di1 * x.w);
}

// ------------------------------------------------ privatized edge scatter ----
__global__ __launch_bounds__(1024) void scatterp_kernel(const int* __restrict__ src,
                                                        const int4* __restrict__ dst4,
                                                        const float2* __restrict__ y,
                                                        float* __restrict__ Tpart,
                                                        unsigned* __restrict__ ticket) {
    __shared__ float T[2 * PART];            // 50 KB
    const int tid = threadIdx.x;
    if (blockIdx.x == 0 && blockIdx.y == 0 && tid == 0)
        __hip_atomic_store(ticket, 0u, __ATOMIC_RELAXED, __HIP_MEMORY_SCOPE_AGENT);
    for (int i = tid; i < 2 * PART; i += 1024) T[i] = 0.f;
    __syncthreads();

    const int base = blockIdx.y * PART;
    const int e0 = blockIdx.x * EPSE;
    const int b0 = blockIdx.x * (EPSE / 4);
    for (int i = tid; i < EPSE / 4; i += 1024) {
        const int4 d = dst4[b0 + i];
        const int e = e0 + 4 * i;
        unsigned r;
        r = (unsigned)(d.x - base);
        if (r < PART) { const float2 ys = y[src[e]];     atomicAdd(&T[2*r], ys.x); atomicAdd(&T[2*r+1], ys.y); }
        r = (unsigned)(d.y - base);
        if (r < PART) { const float2 ys = y[src[e + 1]]; atomicAdd(&T[2*r], ys.x); atomicAdd(&T[2*r+1], ys.y); }
        r = (unsigned)(d.z - base);
        if (r < PART) { const float2 ys = y[src[e + 2]]; atomicAdd(&T[2*r], ys.x); atomicAdd(&T[2*r+1], ys.y); }
        r = (unsigned)(d.w - base);
        if (r < PART) { const float2 ys = y[src[e + 3]]; atomicAdd(&T[2*r], ys.x); atomicAdd(&T[2*r+1], ys.y); }
    }
    __syncthreads();

    float* outp = Tpart + (size_t)blockIdx.x * (2 * N_NODES) + 2 * base;
    for (int i = tid; i < 2 * PART; i += 1024) outp[i] = T[i];
}

// ---- Tpart reduce + LN (lane=node, shuffle-free) + pool + ticket MLP tail ----
// pooled[j] = gamma_j * A_j + N * beta_j,  A_j = sum_n r_n*(v_nj - mu_n)
// Pass 1: lane = node, loop j (LDS broadcast of packed (w0,w1,bg)) -> no
//         cross-lane ops for mean/var. Pass 2: lane = 4 columns, loop nodes.
__global__ __launch_bounds__(256) void ln_pool_mlp_kernel(
    const float* __restrict__ Tpart,
    const float2* __restrict__ y,
    const float* __restrict__ dinv,
    const float* __restrict__ Wg, const float* __restrict__ bg,
    const float* __restrict__ gamma, const float* __restrict__ beta,
    const float* __restrict__ Wh, const float* __restrict__ bh,
    const float* __restrict__ Wo, const float* __restrict__ bo,
    float* __restrict__ Ppart,
    unsigned* __restrict__ ticket,
    float* __restrict__ out)
{
    const int tid  = threadIdx.x;
    const int bid  = blockIdx.x;
    const int n0   = bid * NPB;
    const int lane = tid & 63;
    const int wv   = tid >> 6;

    __shared__ float  Tloc[2 * NPB];     // 2 KB
    __shared__ float4 Wp[HIDDEN];        // 4 KB (w0, w1, bg, -)
    __shared__ float4 nd[4][64];         // 4 KB (s0, s1, r, r*mu)
    __shared__ float  red[4][HIDDEN];    // 4 KB
    __shared__ float  pz[HIDDEN], zz[HIDDEN], lg[OUT_DIM];
    __shared__ int    is_last;

    // stage packed per-column constants
    Wp[tid] = make_float4(Wg[tid], Wg[HIDDEN + tid], bg[tid], 0.f);

    // block-local Tpart reduction (thread covers cols tid, tid+NPB)
    {
        const int lim = 2 * ((N_NODES - n0 < NPB) ? (N_NODES - n0) : NPB);
        const bool gA = tid < lim, gB = tid + NPB < lim;
        float sA = 0.f, sB = 0.f;
        #pragma unroll
        for (int p = 0; p < ES; ++p) {
            const float* row = Tpart + (size_t)p * (2 * N_NODES) + 2 * n0;
            if (gA) sA += row[tid];
            if (gB) sB += row[tid + NPB];
        }
        if (gA) Tloc[tid] = sA;
        if (gB) Tloc[tid + NPB] = sB;
    }
    __syncthreads();

    // ---------------- pass 1: lane = node, mean/var (no cross-lane) -------
    {
        const int n = n0 + tid;
        float s0 = 0.f, s1 = 0.f, r = 0.f, rm = 0.f;
        if (n < N_NODES) {
            const float di = dinv[n];
            const float2 yn = y[n];
            s0 = di * (Tloc[2 * tid]     + yn.x);
            s1 = di * (Tloc[2 * tid + 1] + yn.y);

            float sumA = 0.f, sumB = 0.f, sqA = 0.f, sqB = 0.f;
            #pragma unroll 4
            for (int j = 0; j < HIDDEN; j += 2) {
                const float4 wa = Wp[j];
                const float4 wb = Wp[j + 1];
                const float va = fmaxf(fmaf(s1, wa.y, fmaf(s0, wa.x, wa.z)), 0.f);
                const float vb = fmaxf(fmaf(s1, wb.y, fmaf(s0, wb.x, wb.z)), 0.f);
                sumA += va; sqA = fmaf(va, va, sqA);
                sumB += vb; sqB = fmaf(vb, vb, sqB);
            }
            const float mu  = (sumA + sumB) * (1.0f / HIDDEN);
            const float var = (sqA + sqB) * (1.0f / HIDDEN) - mu * mu;
            r  = rsqrtf(var + LN_EPS);
            rm = r * mu;
        }
        nd[wv][lane] = make_float4(s0, s1, r, rm);
    }
    __syncthreads();

    // ---------------- pass 2: lane = 4 columns, loop 64 nodes -------------
    {
        const float4 w0  = *reinterpret_cast<const float4*>(&Wg[lane * 4]);
        const float4 w1  = *reinterpret_cast<const float4*>(&Wg[HIDDEN + lane * 4]);
        const float4 bgv = *reinterpret_cast<const float4*>(&bg[lane * 4]);

        float a0 = 0.f, a1 = 0.f, a2 = 0.f, a3 = 0.f;
        #pragma unroll 4
        for (int k = 0; k < 64; ++k) {
            const float4 d = nd[wv][k];          // broadcast read
            const float v0 = fmaxf(fmaf(d.y, w1.x, fmaf(d.x, w0.x, bgv.x)), 0.f);
            const float v1 = fmaxf(fmaf(d.y, w1.y, fmaf(d.x, w0.y, bgv.y)), 0.f);
            const float v2 = fmaxf(fmaf(d.y, w1.z, fmaf(d.x, w0.z, bgv.z)), 0.f);
            const float v3 = fmaxf(fmaf(d.y, w1.w, fmaf(d.x, w0.w, bgv.w)), 0.f);
            a0 += fmaf(d.z, v0, -d.w);
            a1 += fmaf(d.z, v1, -d.w);
            a2 += fmaf(d.z, v2, -d.w);
            a3 += fmaf(d.z, v3, -d.w);
        }
        red[wv][lane * 4 + 0] = a0;
        red[wv][lane * 4 + 1] = a1;
        red[wv][lane * 4 + 2] = a2;
        red[wv][lane * 4 + 3] = a3;
    }
    __syncthreads();

    Ppart[(size_t)bid * HIDDEN + tid] =
        red[0][tid] + red[1][tid] + red[2][tid] + red[3][tid];
    __syncthreads();

    // ------------- ticket: last block runs the MLP head -------------------
    if (tid == 0) {
        const unsigned old = __hip_atomic_fetch_add(ticket, 1u, __ATOMIC_ACQ_REL,
                                                    __HIP_MEMORY_SCOPE_AGENT);
        is_last = (old == (unsigned)(gridDim.x - 1));
    }
    __syncthreads();
    if (!is_last) return;

    // pooled = gamma * sum(Ppart) + N * beta
    {
        float S = 0.f;
        for (int b = 0; b < LNB; ++b) S += Ppart[(size_t)b * HIDDEN + tid];
        pz[tid] = gamma[tid] * S + (float)N_NODES * beta[tid];
    }
    __syncthreads();

    // z = relu(bh + pooled @ Wh)
    {
        float acc = bh[tid];
        #pragma unroll 8
        for (int k = 0; k < HIDDEN; ++k) acc = fmaf(pz[k], Wh[k * HIDDEN + tid], acc);
        zz[tid] = fmaxf(acc, 0.f);
    }
    __syncthreads();

    if (tid < OUT_DIM) {
        float t = bo[tid];
        for (int k = 0; k < HIDDEN; ++k) t = fmaf(zz[k], Wo[k * OUT_DIM + tid], t);
        lg[tid] = t;
    }
    __syncthreads();

    if (tid == 0) {
        float m = lg[0];
        for (int k = 1; k < OUT_DIM; ++k) m = fmaxf(m, lg[k]);
        float sum = 0.f;
        for (int k = 0; k < OUT_DIM; ++k) sum += expf(lg[k] - m);
        const float lse = m + logf(sum);
        for (int k = 0; k < OUT_DIM; ++k) out[k] = lg[k] - lse;
    }
}

// ---------------------------------------------------------------- launch ----
extern "C" void kernel_launch(void* const* d_in, const int* in_sizes, int n_in,
                              void* d_out, int out_size, void* d_ws, size_t ws_size,
                              hipStream_t stream) {
    const float* nf    = (const float*)d_in[0];   // [N, 2]
    const int*   ei    = (const int*)  d_in[1];   // [2, E] int32
    const float* Wg    = (const float*)d_in[2];
    const float* bg    = (const float*)d_in[3];
    const float* gamma = (const float*)d_in[4];
    const float* beta  = (const float*)d_in[5];
    const float* Wh    = (const float*)d_in[6];
    const float* bh    = (const float*)d_in[7];
    const float* Wo    = (const float*)d_in[8];
    const float* bo    = (const float*)d_in[9];
    float* out = (float*)d_out;

    const int* srcp = ei;
    const int* dstp = ei + N_EDGES;               // 3.2MB offset: 16B-aligned

    // workspace: ticket u32[16] | degp32 [ES*N/2] u32 (3.2MB)
    //            | Tpart [ES*2N] f32 (12.8MB) | dinv [N] | y [2N] | Ppart [LNB*H]
    unsigned* ticket = (unsigned*)d_ws;
    unsigned* degp32 = ticket + 16;
    float* Tpart  = (float*)(degp32 + (size_t)ES * NH2);
    float* dinvp  = Tpart + (size_t)ES * 2 * N_NODES;
    float* yp     = dinvp + N_NODES;
    float* Ppart  = yp + 2 * N_NODES;

    dim3 pg(ES, NP);
    hist_kernel<<<pg, 1024, 0, stream>>>((const int4*)dstp, degp32);
    dinv_y_kernel<<<(NH2 + 255) / 256, 256, 0, stream>>>(degp32, (const float4*)nf,
                                                         (float2*)dinvp, (float4*)yp);
    scatterp_kernel<<<pg, 1024, 0, stream>>>(srcp, (const int4*)dstp, (const float2*)yp,
                                             Tpart, ticket);
    ln_pool_mlp_kernel<<<LNB, 256, 0, stream>>>(Tpart, (const float2*)yp, dinvp,
                                                Wg, bg, gamma, beta, Wh, bh, Wo, bo,
                                                Ppart, ticket, out);
}

// Round 9
// 62.810 us; speedup vs baseline: 1.3071x; 1.3071x over previous
//
#include <hip/hip_runtime.h>
#include <math.h>

#define N_NODES 50000
#define N_EDGES 800000
#define HIDDEN  256
#define OUT_DIM 10
#define LN_EPS  1e-5f

#define NP    8                    // node partitions
#define PART  (N_NODES / NP)       // 6250 nodes per partition
#define ES    32                   // edge slices
#define EPSE  (N_EDGES / ES)       // 25000 edges per slice
#define NPB   256                  // nodes per ln block
#define LNB   ((N_NODES + NPB - 1) / NPB)   // 196 blocks
#define NH2   (N_NODES / 2)        // 25000 node pairs

// --------------------------------------------------- privatized histogram ----
__global__ __launch_bounds__(1024) void hist_kernel(const int4* __restrict__ dst4,
                                                    unsigned* __restrict__ degp32) {
    __shared__ unsigned hist[PART];          // 25 KB
    const int tid = threadIdx.x;
    for (int i = tid; i < PART; i += 1024) hist[i] = 0u;
    __syncthreads();

    const int base = blockIdx.y * PART;
    const int b0 = blockIdx.x * (EPSE / 4);
    for (int i = tid; i < EPSE / 4; i += 1024) {
        const int4 d = dst4[b0 + i];
        unsigned r;
        r = (unsigned)(d.x - base); if (r < PART) atomicAdd(&hist[r], 1u);
        r = (unsigned)(d.y - base); if (r < PART) atomicAdd(&hist[r], 1u);
        r = (unsigned)(d.z - base); if (r < PART) atomicAdd(&hist[r], 1u);
        r = (unsigned)(d.w - base); if (r < PART) atomicAdd(&hist[r], 1u);
    }
    __syncthreads();

    unsigned* outp = degp32 + (size_t)blockIdx.x * NH2 + base / 2;
    for (int i = tid; i < PART / 2; i += 1024)
        outp[i] = (hist[2 * i] & 0xFFFFu) | (hist[2 * i + 1] << 16);
}

// deg partials -> dinv = rsqrt(deg+1), y = dinv * x   (2 nodes per thread)
__global__ __launch_bounds__(256) void dinv_y_kernel(const unsigned* __restrict__ degp32,
                                                     const float4* __restrict__ nf4,
                                                     float2* __restrict__ dinv2,
                                                     float4* __restrict__ y4) {
    const int t = blockIdx.x * 256 + threadIdx.x;   // pair index
    if (t >= NH2) return;
    unsigned s0 = 0, s1 = 0;
    #pragma unroll
    for (int s = 0; s < ES; ++s) {
        const unsigned d = degp32[(size_t)s * NH2 + t];
        s0 += d & 0xFFFFu;
        s1 += d >> 16;
    }
    const float di0 = rsqrtf((float)s0 + 1.0f);
    const float di1 = rsqrtf((float)s1 + 1.0f);
    dinv2[t] = make_float2(di0, di1);
    const float4 x = nf4[t];
    y4[t] = make_float4(di0 * x.x, di0 * x.y, di1 * x.z, di1 * x.w);
}

// ------------------------------------------------ privatized edge scatter ----
__global__ __launch_bounds__(1024) void scatterp_kernel(const int* __restrict__ src,
                                                        const int4* __restrict__ dst4,
                                                        const float2* __restrict__ y,
                                                        float* __restrict__ Tpart,
                                                        unsigned* __restrict__ ticket) {
    __shared__ float T[2 * PART];            // 50 KB
    const int tid = threadIdx.x;
    if (blockIdx.x == 0 && blockIdx.y == 0 && tid == 0)
        __hip_atomic_store(ticket, 0u, __ATOMIC_RELAXED, __HIP_MEMORY_SCOPE_AGENT);
    for (int i = tid; i < 2 * PART; i += 1024) T[i] = 0.f;
    __syncthreads();

    const int base = blockIdx.y * PART;
    const int e0 = blockIdx.x * EPSE;
    const int b0 = blockIdx.x * (EPSE / 4);
    for (int i = tid; i < EPSE / 4; i += 1024) {
        const int4 d = dst4[b0 + i];
        const int e = e0 + 4 * i;
        unsigned r;
        r = (unsigned)(d.x - base);
        if (r < PART) { const float2 ys = y[src[e]];     atomicAdd(&T[2*r], ys.x); atomicAdd(&T[2*r+1], ys.y); }
        r = (unsigned)(d.y - base);
        if (r < PART) { const float2 ys = y[src[e + 1]]; atomicAdd(&T[2*r], ys.x); atomicAdd(&T[2*r+1], ys.y); }
        r = (unsigned)(d.z - base);
        if (r < PART) { const float2 ys = y[src[e + 2]]; atomicAdd(&T[2*r], ys.x); atomicAdd(&T[2*r+1], ys.y); }
        r = (unsigned)(d.w - base);
        if (r < PART) { const float2 ys = y[src[e + 3]]; atomicAdd(&T[2*r], ys.x); atomicAdd(&T[2*r+1], ys.y); }
    }
    __syncthreads();

    float* outp = Tpart + (size_t)blockIdx.x * (2 * N_NODES) + 2 * base;
    for (int i = tid; i < 2 * PART; i += 1024) outp[i] = T[i];
}

// ---- Tpart reduce + shuffle-free LN + pool + ticket MLP tail (1024 thr) ----
// pooled[j] = gamma_j * A_j + N * beta_j,  A_j = sum_n r_n*(v_nj - mu_n)
__global__ __launch_bounds__(1024) void ln_pool_mlp_kernel(
    const float* __restrict__ Tpart,
    const float2* __restrict__ y,
    const float* __restrict__ dinv,
    const float* __restrict__ Wg, const float* __restrict__ bg,
    const float* __restrict__ gamma, const float* __restrict__ beta,
    const float* __restrict__ Wh, const float* __restrict__ bh,
    const float* __restrict__ Wo, const float* __restrict__ bo,
    float* __restrict__ Ppart,
    unsigned* __restrict__ ticket,
    float* __restrict__ out)
{
    const int tid  = threadIdx.x;
    const int bid  = blockIdx.x;
    const int n0   = bid * NPB;
    const int lane = tid & 63;
    const int wv   = tid >> 6;

    __shared__ float4 Wp[HIDDEN];        // 4 KB (w0, w1, bg, -)
    __shared__ float  Tred[2][2 * NPB];  // 4 KB
    __shared__ float  ps[4][HIDDEN];     // 4 KB
    __shared__ float  qs[4][HIDDEN];     // 4 KB
    __shared__ float4 nd[NPB];           // 4 KB (s0, s1, r, r*mu)
    __shared__ float  red[16][HIDDEN];   // 16 KB
    __shared__ float  pz[HIDDEN], zz[HIDDEN], lg[OUT_DIM];
    __shared__ int    is_last;

    if (tid < HIDDEN)
        Wp[tid] = make_float4(Wg[tid], Wg[HIDDEN + tid], bg[tid], 0.f);

    // Tpart reduce: 2 slice-groups x 512 cols, 16 loads each
    {
        const int c = tid & 511;
        const int g = tid >> 9;
        const int lim = 2 * ((N_NODES - n0 < NPB) ? (N_NODES - n0) : NPB);
        if (c < lim) {
            float s = 0.f;
            #pragma unroll
            for (int p = 0; p < 16; ++p)
                s += Tpart[(size_t)(g * 16 + p) * (2 * N_NODES) + 2 * n0 + c];
            Tred[g][c] = s;
        }
    }
    __syncthreads();

    // node record init: s0, s1
    if (tid < NPB) {
        const int n = n0 + tid;
        float s0 = 0.f, s1 = 0.f;
        if (n < N_NODES) {
            const float di = dinv[n];
            const float2 yn = y[n];
            s0 = di * (Tred[0][2 * tid]     + Tred[1][2 * tid]     + yn.x);
            s1 = di * (Tred[0][2 * tid + 1] + Tred[1][2 * tid + 1] + yn.y);
        }
        nd[tid] = make_float4(s0, s1, 0.f, 0.f);
    }
    __syncthreads();

    // pass 1: 4 j-groups x 256 nodes, each thread sums 64 cols of its node
    {
        const int nl = tid & 255;
        const int jg = tid >> 8;
        const float4 d = nd[nl];
        float sumA = 0.f, sumB = 0.f, sqA = 0.f, sqB = 0.f;
        #pragma unroll 8
        for (int j = jg * 64; j < jg * 64 + 64; j += 2) {
            const float4 wa = Wp[j];
            const float4 wb = Wp[j + 1];
            const float va = fmaxf(fmaf(d.y, wa.y, fmaf(d.x, wa.x, wa.z)), 0.f);
            const float vb = fmaxf(fmaf(d.y, wb.y, fmaf(d.x, wb.x, wb.z)), 0.f);
            sumA += va; sqA = fmaf(va, va, sqA);
            sumB += vb; sqB = fmaf(vb, vb, sqB);
        }
        ps[jg][nl] = sumA + sumB;
        qs[jg][nl] = sqA + sqB;
    }
    __syncthreads();

    // finalize per-node r, r*mu
    if (tid < NPB) {
        const float sum = ps[0][tid] + ps[1][tid] + ps[2][tid] + ps[3][tid];
        const float sq  = qs[0][tid] + qs[1][tid] + qs[2][tid] + qs[3][tid];
        const float mu  = sum * (1.0f / HIDDEN);
        const float var = sq * (1.0f / HIDDEN) - mu * mu;
        float r  = rsqrtf(var + LN_EPS);
        float rm = r * mu;
        if (n0 + tid >= N_NODES) { r = 0.f; rm = 0.f; }
        const float4 d = nd[tid];
        nd[tid] = make_float4(d.x, d.y, r, rm);
    }
    __syncthreads();

    // pass 2: 16 waves x 16 nodes, lane = 4 columns
    {
        const float4 w0  = *reinterpret_cast<const float4*>(&Wg[lane * 4]);
        const float4 w1  = *reinterpret_cast<const float4*>(&Wg[HIDDEN + lane * 4]);
        const float4 bgv = *reinterpret_cast<const float4*>(&bg[lane * 4]);

        float a0 = 0.f, a1 = 0.f, a2 = 0.f, a3 = 0.f;
        #pragma unroll
        for (int k = 0; k < 16; ++k) {
            const float4 d = nd[wv * 16 + k];    // broadcast read
            const float v0 = fmaxf(fmaf(d.y, w1.x, fmaf(d.x, w0.x, bgv.x)), 0.f);
            const float v1 = fmaxf(fmaf(d.y, w1.y, fmaf(d.x, w0.y, bgv.y)), 0.f);
            const float v2 = fmaxf(fmaf(d.y, w1.z, fmaf(d.x, w0.z, bgv.z)), 0.f);
            const float v3 = fmaxf(fmaf(d.y, w1.w, fmaf(d.x, w0.w, bgv.w)), 0.f);
            a0 += fmaf(d.z, v0, -d.w);
            a1 += fmaf(d.z, v1, -d.w);
            a2 += fmaf(d.z, v2, -d.w);
            a3 += fmaf(d.z, v3, -d.w);
        }
        red[wv][lane * 4 + 0] = a0;
        red[wv][lane * 4 + 1] = a1;
        red[wv][lane * 4 + 2] = a2;
        red[wv][lane * 4 + 3] = a3;
    }
    __syncthreads();

    if (tid < HIDDEN) {
        float s = 0.f;
        #pragma unroll
        for (int w = 0; w < 16; ++w) s += red[w][tid];
        Ppart[(size_t)bid * HIDDEN + tid] = s;
    }
    __syncthreads();

    // ------------- ticket: last block runs the MLP head -------------------
    if (tid == 0) {
        const unsigned old = __hip_atomic_fetch_add(ticket, 1u, __ATOMIC_ACQ_REL,
                                                    __HIP_MEMORY_SCOPE_AGENT);
        is_last = (old == (unsigned)(gridDim.x - 1));
    }
    __syncthreads();
    if (!is_last) return;

    // pooled = gamma * sum(Ppart) + N * beta   (4-way split over blocks)
    {
        const int g = tid >> 8;
        const int j = tid & 255;
        float s = 0.f;
        for (int b = g; b < LNB; b += 4) s += Ppart[(size_t)b * HIDDEN + j];
        ps[g][j] = s;
    }
    __syncthreads();
    if (tid < HIDDEN) {
        const float S = ps[0][tid] + ps[1][tid] + ps[2][tid] + ps[3][tid];
        pz[tid] = gamma[tid] * S + (float)N_NODES * beta[tid];
    }
    __syncthreads();

    // z = relu(bh + pooled @ Wh)   (4-way split over k)
    {
        const int g = tid >> 8;
        const int j = tid & 255;
        float acc = 0.f;
        #pragma unroll 8
        for (int k = g * 64; k < g * 64 + 64; ++k)
            acc = fmaf(pz[k], Wh[k * HIDDEN + j], acc);
        qs[g][j] = acc;
    }
    __syncthreads();
    if (tid < HIDDEN)
        zz[tid] = fmaxf(bh[tid] + qs[0][tid] + qs[1][tid] + qs[2][tid] + qs[3][tid], 0.f);
    __syncthreads();

    // logits = z @ Wo + bo  (one wave per output)
    if (wv < OUT_DIM) {
        float acc = 0.f;
        #pragma unroll
        for (int q = 0; q < 4; ++q) {
            const int k = lane + 64 * q;
            acc = fmaf(zz[k], Wo[k * OUT_DIM + wv], acc);
        }
        #pragma unroll
        for (int o = 1; o < 64; o <<= 1) acc += __shfl_xor(acc, o, 64);
        if (lane == 0) lg[wv] = acc + bo[wv];
    }
    __syncthreads();

    if (tid == 0) {
        float m = lg[0];
        for (int k = 1; k < OUT_DIM; ++k) m = fmaxf(m, lg[k]);
        float sum = 0.f;
        for (int k = 0; k < OUT_DIM; ++k) sum += expf(lg[k] - m);
        const float lse = m + logf(sum);
        for (int k = 0; k < OUT_DIM; ++k) out[k] = lg[k] - lse;
    }
}

// ---------------------------------------------------------------- launch ----
extern "C" void kernel_launch(void* const* d_in, const int* in_sizes, int n_in,
                              void* d_out, int out_size, void* d_ws, size_t ws_size,
                              hipStream_t stream) {
    const float* nf    = (const float*)d_in[0];   // [N, 2]
    const int*   ei    = (const int*)  d_in[1];   // [2, E] int32
    const float* Wg    = (const float*)d_in[2];
    const float* bg    = (const float*)d_in[3];
    const float* gamma = (const float*)d_in[4];
    const float* beta  = (const float*)d_in[5];
    const float* Wh    = (const float*)d_in[6];
    const float* bh    = (const float*)d_in[7];
    const float* Wo    = (const float*)d_in[8];
    const float* bo    = (const float*)d_in[9];
    float* out = (float*)d_out;

    const int* srcp = ei;
    const int* dstp = ei + N_EDGES;               // 3.2MB offset: 16B-aligned

    // workspace: ticket u32[16] | degp32 [ES*N/2] u32 (3.2MB)
    //            | Tpart [ES*2N] f32 (12.8MB) | dinv [N] | y [2N] | Ppart [LNB*H]
    unsigned* ticket = (unsigned*)d_ws;
    unsigned* degp32 = ticket + 16;
    float* Tpart  = (float*)(degp32 + (size_t)ES * NH2);
    float* dinvp  = Tpart + (size_t)ES * 2 * N_NODES;
    float* yp     = dinvp + N_NODES;
    float* Ppart  = yp + 2 * N_NODES;

    dim3 pg(ES, NP);
    hist_kernel<<<pg, 1024, 0, stream>>>((const int4*)dstp, degp32);
    dinv_y_kernel<<<(NH2 + 255) / 256, 256, 0, stream>>>(degp32, (const float4*)nf,
                                                         (float2*)dinvp, (float4*)yp);
    scatterp_kernel<<<pg, 1024, 0, stream>>>(srcp, (const int4*)dstp, (const float2*)yp,
                                             Tpart, ticket);
    ln_pool_mlp_kernel<<<LNB, 1024, 0, stream>>>(Tpart, (const float2*)yp, dinvp,
                                                 Wg, bg, gamma, beta, Wh, bh, Wo, bo,
                                                 Ppart, ticket, out);
}